// Round 5
// baseline (171.041 us; speedup 1.0000x reference)
//
#include <hip/hip_runtime.h>

// B=4, H=W=128, D=64, NH=2, hd=32, 9 taps. All inputs fp32; compute fp16 MFMA.
// R5: restore occupancy. attn: 512-thr blocks (2 rows), 152 KB staged once,
// 2 waves/SIMD. convs: N-split blocks (72 KB LDS) -> 2 blocks/CU, 4 waves/SIMD.
// Barrier-free tap loops with A-rotation kept from R4.

typedef _Float16 half8 __attribute__((ext_vector_type(8)));
typedef _Float16 half4v __attribute__((ext_vector_type(4)));
typedef float f32x4 __attribute__((ext_vector_type(4)));

__device__ __forceinline__ f32x4 mfma16(half8 a, half8 b, f32x4 c) {
  return __builtin_amdgcn_mfma_f32_16x16x32_f16(a, b, c, 0, 0, 0);
}
__device__ __forceinline__ half8 ldfrag(const _Float16* p) { return *(const half8*)p; }
__device__ __forceinline__ half8 zfrag() { half8 z = {}; return z; }

__device__ __forceinline__ void gload_lds16(const _Float16* g, _Float16* l) {
  __builtin_amdgcn_global_load_lds(
      (const __attribute__((address_space(1))) void*)g,
      (__attribute__((address_space(3))) void*)l, 16, 0, 0);
}

// ---------------- x -> fp16 ----------------
__global__ __launch_bounds__(256) void cvt_x(const float* __restrict__ x,
                                             _Float16* __restrict__ xh) {
  int i = blockIdx.x * 256 + threadIdx.x;
  float4 v = ((const float4*)x)[i];
  half4v h = { (_Float16)v.x, (_Float16)v.y, (_Float16)v.z, (_Float16)v.w };
  *(half4v*)(xh + i * 4) = h;
}

// ---------------- weight repack into MFMA fragment layouts ----------------
// Fragment = 64 lanes x 8 halves (1 KB). A-frag: A[m=l15][k=q8+j]. B-frag: B[k][n=l15].
//   AQ  [mb4][kb2]      @ 0       AK  [t9][cb4][kb2]  @ 4096
//   BV  [t9][kb2][nb4]  @ 40960   B1  [kb2][nb4]      @ 77824
//   BF2 [t9][kb2][nb8]  @ 81920   BF3 [t9][kb4][nb4]  @ 155648  (229376 total)
__global__ __launch_bounds__(256) void repack(
    const float* __restrict__ Kp, const float* __restrict__ Vp,
    const float* __restrict__ Qp, const float* __restrict__ W1,
    const float* __restrict__ F2, const float* __restrict__ F3,
    _Float16* __restrict__ out) {
  int e = blockIdx.x * 256 + threadIdx.x;
  int j = e & 7, l = (e >> 3) & 63, f = e >> 9;
  int l15 = l & 15, q8 = (l >> 4) * 8;
  float v;
  if (f < 8)        { int mb = f >> 1, kb = f & 1;
                      v = Qp[(kb*32 + q8 + j) * 64 + mb*16 + l15]; }
  else if (f < 80)  { int g = f - 8, t = g >> 3, mb = (g >> 1) & 3, kb = g & 1;
                      v = Kp[(kb*32 + q8 + j) * 576 + t*64 + mb*16 + l15]; }
  else if (f < 152) { int g = f - 80, t = g >> 3, kb = (g >> 2) & 1, nb = g & 3;
                      v = Vp[(kb*32 + q8 + j) * 576 + t*64 + nb*16 + l15]; }
  else if (f < 160) { int g = f - 152, kb = g >> 2, nb = g & 3;
                      v = W1[(kb*32 + q8 + j) * 64 + nb*16 + l15]; }
  else if (f < 304) { int g = f - 160, t = g >> 4, kb = (g >> 3) & 1, nb = g & 7;
                      v = F2[(t*64 + kb*32 + q8 + j) * 128 + nb*16 + l15]; }
  else              { int g = f - 304, t = g >> 4, kb = (g >> 2) & 3, nb = g & 3;
                      v = F3[(t*128 + kb*32 + q8 + j) * 64 + nb*16 + l15]; }
  out[e] = (_Float16)v;
}

// ---------------- attention + ff1 ----------------
// 512 threads = 8 waves; block = 2 rows; wave = 32 px (m=2). LDS (halves):
// AK[0,36864) BV[36864,73728) B1[73728,77824). Staged ONCE; barrier-free taps.
__global__ __launch_bounds__(512, 2) void attn_ff1(
    const _Float16* __restrict__ xh, const _Float16* __restrict__ wf,
    const float* __restrict__ f1b, _Float16* __restrict__ t1g) {
  extern __shared__ _Float16 smem[];
  const int lane = threadIdx.x & 63, wid = threadIdx.x >> 6;
  const int l15 = lane & 15, q8 = (lane >> 4) * 8;
  const int row = blockIdx.x * 2 + (wid >> 2);
  const int rw = wid & 3;
  const int p0 = row * 128 + rw * 32;
  const int h = row & 127;
  const int w0 = rw * 32;

  // stage ALL weights (152 frags, 19/wave), in flight during q^T + prologue
  {
    const _Float16* gw = wf + 4096 + (size_t)(wid * 19) * 512;
    _Float16* lw = smem + wid * 19 * 512;
    for (int i = 0; i < 19; ++i)
      gload_lds16(gw + i * 512 + lane * 8, lw + i * 512);
  }

  // own-x fragments + q^T tiles (global reads overlap staging)
  half8 ax0[2], ax1[2];
#pragma unroll
  for (int m = 0; m < 2; ++m) {
    const _Float16* xp = xh + (size_t)(p0 + m * 16 + l15) * 64 + q8;
    ax0[m] = ldfrag(xp); ax1[m] = ldfrag(xp + 32);
  }
  f32x4 qT[2][4];
#pragma unroll
  for (int cb = 0; cb < 4; ++cb) {
    half8 aq0 = ldfrag(wf + (cb * 2 + 0) * 512 + lane * 8);
    half8 aq1 = ldfrag(wf + (cb * 2 + 1) * 512 + lane * 8);
#pragma unroll
    for (int m = 0; m < 2; ++m) {
      f32x4 c = {};
      c = mfma16(aq0, ax0[m], c);
      c = mfma16(aq1, ax1[m], c);
      qT[m][cb] = c;
    }
  }

  // pass-1 tap-0 prologue loads BEFORE the barrier (overlap staging drain)
  half8 sx0[2], sx1[2];
  {
    const bool rk = (unsigned)(h - 1) < 128u;
#pragma unroll
    for (int m = 0; m < 2; ++m) {
      const bool cv = rk && ((unsigned)(w0 + m * 16 + l15 - 1) < 128u);
      const _Float16* sp = xh + (size_t)(p0 + m * 16 + l15 - 129) * 64 + q8;
      sx0[m] = cv ? ldfrag(sp) : zfrag();
      sx1[m] = cv ? ldfrag(sp + 32) : zfrag();
    }
  }

  __syncthreads();                         // staging complete

  // -------- pass 1: scores, barrier-free with A rotation --------------------
  float sc[2][2][9];
#pragma unroll
  for (int t = 0; t < 9; ++t) {
    const int dh = t / 3 - 1;
    const bool rowok = (unsigned)(h + dh) < 128u;
    half8 nx0[2], nx1[2];
    if (t < 8) {                            // prefetch tap t+1 BEFORE compute
      const int dh2 = (t + 1) / 3 - 1, dw2 = (t + 1) % 3 - 1;
      const bool rk2 = (unsigned)(h + dh2) < 128u;
#pragma unroll
      for (int m = 0; m < 2; ++m) {
        const bool cv = rk2 && ((unsigned)(w0 + m * 16 + l15 + dw2) < 128u);
        const _Float16* sp = xh + (size_t)(p0 + m * 16 + l15 + dh2 * 128 + dw2) * 64 + q8;
        nx0[m] = cv ? ldfrag(sp) : zfrag();
        nx1[m] = cv ? ldfrag(sp + 32) : zfrag();
      }
    }
    if (rowok) {
      half8 kf[8];
#pragma unroll
      for (int f = 0; f < 8; ++f) kf[f] = ldfrag(smem + (t * 8 + f) * 512 + lane * 8);
#pragma unroll
      for (int m = 0; m < 2; ++m) {
        float pa = 0.f, pb = 0.f;
#pragma unroll
        for (int cb = 0; cb < 4; ++cb) {
          f32x4 c = {};
          c = mfma16(kf[cb * 2 + 0], sx0[m], c);
          c = mfma16(kf[cb * 2 + 1], sx1[m], c);
          float d = qT[m][cb].x * c.x + qT[m][cb].y * c.y
                  + qT[m][cb].z * c.z + qT[m][cb].w * c.w;
          if (cb < 2) pa += d; else pb += d;
        }
        pa += __shfl_xor(pa, 16, 64); pa += __shfl_xor(pa, 32, 64);
        pb += __shfl_xor(pb, 16, 64); pb += __shfl_xor(pb, 32, 64);
        sc[m][0][t] = pa * (1.f / 3.f);
        sc[m][1][t] = pb * (1.f / 3.f);
      }
    } else {
#pragma unroll
      for (int m = 0; m < 2; ++m) { sc[m][0][t] = 0.f; sc[m][1][t] = 0.f; }
    }
    if (t < 8) {
#pragma unroll
      for (int m = 0; m < 2; ++m) { sx0[m] = nx0[m]; sx1[m] = nx1[m]; }
    }
  }

  // -------- softmax over taps (per lane = per pixel) ------------------------
#pragma unroll
  for (int m = 0; m < 2; ++m)
#pragma unroll
    for (int hd = 0; hd < 2; ++hd) {
      float mx = sc[m][hd][0];
#pragma unroll
      for (int t = 1; t < 9; ++t) mx = fmaxf(mx, sc[m][hd][t]);
      float s = 0.f;
#pragma unroll
      for (int t = 0; t < 9; ++t) { sc[m][hd][t] = __expf(sc[m][hd][t] - mx); s += sc[m][hd][t]; }
      s = 1.f / s;
#pragma unroll
      for (int t = 0; t < 9; ++t) sc[m][hd][t] *= s;
    }

  // -------- pass 2: (alpha*x_shift) @ V, barrier-free -----------------------
  const _Float16* BVl = smem + 36864;
  f32x4 at[2][4];
#pragma unroll
  for (int m = 0; m < 2; ++m)
#pragma unroll
    for (int nb = 0; nb < 4; ++nb) at[m][nb] = f32x4{};
  {
    const bool rk = (unsigned)(h - 1) < 128u;
#pragma unroll
    for (int m = 0; m < 2; ++m) {
      const bool cv = rk && ((unsigned)(w0 + m * 16 + l15 - 1) < 128u);
      const _Float16* sp = xh + (size_t)(p0 + m * 16 + l15 - 129) * 64 + q8;
      sx0[m] = cv ? ldfrag(sp) : zfrag();
      sx1[m] = cv ? ldfrag(sp + 32) : zfrag();
    }
  }
#pragma unroll
  for (int t = 0; t < 9; ++t) {
    const int dh = t / 3 - 1;
    const bool rowok = (unsigned)(h + dh) < 128u;
    half8 nx0[2], nx1[2];
    if (t < 8) {
      const int dh2 = (t + 1) / 3 - 1, dw2 = (t + 1) % 3 - 1;
      const bool rk2 = (unsigned)(h + dh2) < 128u;
#pragma unroll
      for (int m = 0; m < 2; ++m) {
        const bool cv = rk2 && ((unsigned)(w0 + m * 16 + l15 + dw2) < 128u);
        const _Float16* sp = xh + (size_t)(p0 + m * 16 + l15 + dh2 * 128 + dw2) * 64 + q8;
        nx0[m] = cv ? ldfrag(sp) : zfrag();
        nx1[m] = cv ? ldfrag(sp + 32) : zfrag();
      }
    }
    if (rowok) {
      half8 vf[8];
#pragma unroll
      for (int f = 0; f < 8; ++f) vf[f] = ldfrag(BVl + (t * 8 + f) * 512 + lane * 8);
#pragma unroll
      for (int m = 0; m < 2; ++m) {
        _Float16 h0 = (_Float16)sc[m][0][t], h1 = (_Float16)sc[m][1][t];
        half8 b0 = {h0, h0, h0, h0, h0, h0, h0, h0};
        half8 b1 = {h1, h1, h1, h1, h1, h1, h1, h1};
        half8 s00 = sx0[m] * b0, s01 = sx1[m] * b0;
        half8 s10 = sx0[m] * b1, s11 = sx1[m] * b1;
#pragma unroll
        for (int nb = 0; nb < 2; ++nb) {
          at[m][nb]     = mfma16(s00, vf[0 * 4 + nb],     at[m][nb]);
          at[m][nb]     = mfma16(s01, vf[1 * 4 + nb],     at[m][nb]);
          at[m][nb + 2] = mfma16(s10, vf[0 * 4 + nb + 2], at[m][nb + 2]);
          at[m][nb + 2] = mfma16(s11, vf[1 * 4 + nb + 2], at[m][nb + 2]);
        }
      }
    }
    if (t < 8) {
#pragma unroll
      for (int m = 0; m < 2; ++m) { sx0[m] = nx0[m]; sx1[m] = nx1[m]; }
    }
  }

  // -------- ff1: transpose tiles overlay AK region --------------------------
  __syncthreads();                         // all waves done reading AK/BV
  _Float16* myt = smem + wid * 2304;       // 8 x 2304 = 36 KB < AK region
#pragma unroll
  for (int m = 0; m < 2; ++m)
#pragma unroll
    for (int nb = 0; nb < 4; ++nb)
#pragma unroll
      for (int r = 0; r < 4; ++r)
        myt[m * 1152 + ((lane >> 4) * 4 + r) * 72 + nb * 16 + l15] = (_Float16)at[m][nb][r];
  const _Float16* B1l = smem + 73728;
#pragma unroll
  for (int m = 0; m < 2; ++m) {
    half8 aa0 = ldfrag(myt + m * 1152 + l15 * 72 + q8);
    half8 aa1 = ldfrag(myt + m * 1152 + l15 * 72 + 32 + q8);
#pragma unroll
    for (int nb = 0; nb < 4; ++nb) {
      f32x4 c = {};
      c = mfma16(aa0, ldfrag(B1l + (0 * 4 + nb) * 512 + lane * 8), c);
      c = mfma16(aa1, ldfrag(B1l + (1 * 4 + nb) * 512 + lane * 8), c);
      float bv = f1b[nb * 16 + l15];
#pragma unroll
      for (int r = 0; r < 4; ++r) {
        float v = fmaxf(c[r] + bv, 0.f);
        t1g[(size_t)(p0 + m * 16 + (lane >> 4) * 4 + r) * 64 + nb * 16 + l15] = (_Float16)v;
      }
    }
  }
}

// ---------------- 3x3 conv, N-split: block = 2 rows x (COUT/2) channels ----
// KB k-frags, NBL n-frags per block (half of full N). LDS = 9*KB*NBL KB = 72 KB
// -> 2 blocks/CU, 16 waves/CU. Barrier-free tap loop, A rotation.
template <int KB, int NBL, int COUT>
__global__ __launch_bounds__(512, 4) void conv3x3(
    const _Float16* __restrict__ in, const _Float16* __restrict__ wfrag,
    const float* __restrict__ bias, void* __restrict__ outp, int out_fp32) {
  extern __shared__ _Float16 smem[];
  const int lane = threadIdx.x & 63, wid = threadIdx.x >> 6;
  const int l15 = lane & 15, q8 = (lane >> 4) * 8;
  const int nh = blockIdx.x & 1;           // N-half
  const int pairIdx = blockIdx.x >> 1;
  const int row = pairIdx * 2 + (wid >> 2);
  const int rw = wid & 3;
  const int p0 = row * 128 + rw * 32;
  const int h = row & 127;
  const int w0 = rw * 32;
  const int CIN = KB * 32;
  const int NBF = COUT / 16;               // full n-frags per (t,kb)

  // stage this half's 72 frags (9 per wave): local f -> t=f/8, kb=(f%8)/NBL, i=f%NBL
  {
    for (int s = 0; s < 9; ++s) {
      int f = wid * 9 + s;
      int t = f >> 3, r = f & 7, kb = r / NBL, i = r % NBL;
      const _Float16* g = wfrag + (size_t)((t * KB + kb) * NBF + nh * NBL + i) * 512;
      gload_lds16(g + lane * 8, smem + f * 512);
    }
  }

  f32x4 acc[2][NBL];
#pragma unroll
  for (int m = 0; m < 2; ++m)
#pragma unroll
    for (int nb = 0; nb < NBL; ++nb) acc[m][nb] = f32x4{};

  // tap-0 prologue A-loads BEFORE the barrier (overlap staging)
  half8 a[2][KB];
  {
    const bool rk = (unsigned)(h - 1) < 128u;
#pragma unroll
    for (int m = 0; m < 2; ++m) {
      const bool cv = rk && ((unsigned)(w0 + m * 16 + l15 - 1) < 128u);
      const _Float16* sp = in + (size_t)(p0 + m * 16 + l15 - 129) * CIN + q8;
#pragma unroll
      for (int kb = 0; kb < KB; ++kb) a[m][kb] = cv ? ldfrag(sp + kb * 32) : zfrag();
    }
  }

  __syncthreads();                         // the only barrier

#pragma unroll
  for (int t = 0; t < 9; ++t) {
    const int dh = t / 3 - 1;
    const bool rowok = (unsigned)(h + dh) < 128u;
    half8 an[2][KB];
    if (t < 8) {                            // prefetch tap t+1 BEFORE compute
      const int dh2 = (t + 1) / 3 - 1, dw2 = (t + 1) % 3 - 1;
      const bool rk2 = (unsigned)(h + dh2) < 128u;
#pragma unroll
      for (int m = 0; m < 2; ++m) {
        const bool cv = rk2 && ((unsigned)(w0 + m * 16 + l15 + dw2) < 128u);
        const _Float16* sp = in + (size_t)(p0 + m * 16 + l15 + dh2 * 128 + dw2) * CIN + q8;
#pragma unroll
        for (int kb = 0; kb < KB; ++kb) an[m][kb] = cv ? ldfrag(sp + kb * 32) : zfrag();
      }
    }
    if (rowok) {
#pragma unroll
      for (int nb = 0; nb < NBL; ++nb) {
#pragma unroll
        for (int kb = 0; kb < KB; ++kb) {
          half8 b = ldfrag(smem + (size_t)((t * KB + kb) * NBL + nb) * 512 + lane * 8);
          acc[0][nb] = mfma16(a[0][kb], b, acc[0][nb]);
          acc[1][nb] = mfma16(a[1][kb], b, acc[1][nb]);
        }
      }
    }
    if (t < 8) {
#pragma unroll
      for (int m = 0; m < 2; ++m)
#pragma unroll
        for (int kb = 0; kb < KB; ++kb) a[m][kb] = an[m][kb];
    }
  }

#pragma unroll
  for (int m = 0; m < 2; ++m)
#pragma unroll
    for (int nb = 0; nb < NBL; ++nb) {
      float bv = bias[nh * NBL * 16 + nb * 16 + l15];
#pragma unroll
      for (int r = 0; r < 4; ++r) {
        float v = fmaxf(acc[m][nb][r] + bv, 0.f);
        size_t idx = (size_t)(p0 + m * 16 + (lane >> 4) * 4 + r) * COUT
                   + nh * NBL * 16 + nb * 16 + l15;
        if (out_fp32) ((float*)outp)[idx] = v;
        else          ((_Float16*)outp)[idx] = (_Float16)v;
      }
    }
}

extern "C" void kernel_launch(void* const* d_in, const int* in_sizes, int n_in,
                              void* d_out, int out_size, void* d_ws, size_t ws_size,
                              hipStream_t stream) {
  (void)in_sizes; (void)n_in; (void)out_size; (void)ws_size;
  const float* x   = (const float*)d_in[0];
  const float* Kp  = (const float*)d_in[1];
  const float* Vp  = (const float*)d_in[2];
  const float* Qp  = (const float*)d_in[3];
  const float* f1w = (const float*)d_in[4];
  const float* f1b = (const float*)d_in[5];
  const float* f2w = (const float*)d_in[6];
  const float* f2b = (const float*)d_in[7];
  const float* f3w = (const float*)d_in[8];
  const float* f3b = (const float*)d_in[9];

  _Float16* xh  = (_Float16*)d_ws;
  _Float16* wf  = xh + 4194304;
  _Float16* t2g = wf + 229376;
  _Float16* t1g = (_Float16*)d_out;   // fp16 t1 in d_out, overwritten by conv3

  (void)hipFuncSetAttribute((const void*)attn_ff1,
      hipFuncAttributeMaxDynamicSharedMemorySize, 155648);
  (void)hipFuncSetAttribute((const void*)conv3x3<2, 4, 128>,
      hipFuncAttributeMaxDynamicSharedMemorySize, 73728);
  (void)hipFuncSetAttribute((const void*)conv3x3<4, 2, 64>,
      hipFuncAttributeMaxDynamicSharedMemorySize, 73728);

  cvt_x<<<4096, 256, 0, stream>>>(x, xh);
  repack<<<896, 256, 0, stream>>>(Kp, Vp, Qp, f1w, f2w, f3w, wf);
  attn_ff1<<<256, 512, 155648, stream>>>(xh, wf, f1b, t1g);
  conv3x3<2, 4, 128><<<512, 512, 73728, stream>>>(t1g, wf + 81920, f2b, t2g, 0);
  conv3x3<4, 2, 64><<<512, 512, 73728, stream>>>(t2g, wf + 155648, f3b, d_out, 1);
}

// Round 6
// 166.042 us; speedup vs baseline: 1.0301x; 1.0301x over previous
//
#include <hip/hip_runtime.h>

// B=4, H=W=128, D=64, NH=2, hd=32, 9 taps. All inputs fp32; compute fp16 MFMA.
// R6: attn uses fused one-pass online softmax (no-max; scores bounded):
//   per tap: sc_t -> e=exp(sc_t) -> acc += e*(x_t @ V_t), den += e; divide at end.
// cvt_x+repack merged into one prep kernel. Convs = R5 shape, lb(512,2).

typedef _Float16 half8 __attribute__((ext_vector_type(8)));
typedef _Float16 half4v __attribute__((ext_vector_type(4)));
typedef float f32x4 __attribute__((ext_vector_type(4)));

__device__ __forceinline__ f32x4 mfma16(half8 a, half8 b, f32x4 c) {
  return __builtin_amdgcn_mfma_f32_16x16x32_f16(a, b, c, 0, 0, 0);
}
__device__ __forceinline__ half8 ldfrag(const _Float16* p) { return *(const half8*)p; }
__device__ __forceinline__ half8 zfrag() { half8 z = {}; return z; }

__device__ __forceinline__ void gload_lds16(const _Float16* g, _Float16* l) {
  __builtin_amdgcn_global_load_lds(
      (const __attribute__((address_space(1))) void*)g,
      (__attribute__((address_space(3))) void*)l, 16, 0, 0);
}

// ---------------- prep: x->fp16 convert + weight repack, one kernel --------
// blocks [0,4096): cvt (256 thr x 4 floats); blocks [4096,4992): repack.
// Fragment = 64 lanes x 8 halves (1 KB). A-frag: A[m=l15][k=q8+j]. B: B[k][n=l15].
//   AQ  [mb4][kb2]      @ 0       AK  [t9][cb4][kb2]  @ 4096
//   BV  [t9][kb2][nb4]  @ 40960   B1  [kb2][nb4]      @ 77824
//   BF2 [t9][kb2][nb8]  @ 81920   BF3 [t9][kb4][nb4]  @ 155648  (229376 total)
__global__ __launch_bounds__(256) void prep(
    const float* __restrict__ x, const float* __restrict__ Kp,
    const float* __restrict__ Vp, const float* __restrict__ Qp,
    const float* __restrict__ W1, const float* __restrict__ F2,
    const float* __restrict__ F3, _Float16* __restrict__ xh,
    _Float16* __restrict__ out) {
  if (blockIdx.x < 4096) {
    int i = blockIdx.x * 256 + threadIdx.x;
    float4 v = ((const float4*)x)[i];
    half4v h = { (_Float16)v.x, (_Float16)v.y, (_Float16)v.z, (_Float16)v.w };
    *(half4v*)(xh + i * 4) = h;
    return;
  }
  int e = (blockIdx.x - 4096) * 256 + threadIdx.x;  // 229376 total
  int j = e & 7, l = (e >> 3) & 63, f = e >> 9;
  int l15 = l & 15, q8 = (l >> 4) * 8;
  float v;
  if (f < 8)        { int mb = f >> 1, kb = f & 1;
                      v = Qp[(kb*32 + q8 + j) * 64 + mb*16 + l15]; }
  else if (f < 80)  { int g = f - 8, t = g >> 3, mb = (g >> 1) & 3, kb = g & 1;
                      v = Kp[(kb*32 + q8 + j) * 576 + t*64 + mb*16 + l15]; }
  else if (f < 152) { int g = f - 80, t = g >> 3, kb = (g >> 2) & 1, nb = g & 3;
                      v = Vp[(kb*32 + q8 + j) * 576 + t*64 + nb*16 + l15]; }
  else if (f < 160) { int g = f - 152, kb = g >> 2, nb = g & 3;
                      v = W1[(kb*32 + q8 + j) * 64 + nb*16 + l15]; }
  else if (f < 304) { int g = f - 160, t = g >> 4, kb = (g >> 3) & 1, nb = g & 7;
                      v = F2[(t*64 + kb*32 + q8 + j) * 128 + nb*16 + l15]; }
  else              { int g = f - 304, t = g >> 4, kb = (g >> 2) & 3, nb = g & 3;
                      v = F3[(t*128 + kb*32 + q8 + j) * 64 + nb*16 + l15]; }
  out[e] = (_Float16)v;
}

// ---------------- attention + ff1, fused one-pass softmax ------------------
// 512 thr = 8 waves; block = 2 rows; wave = 32 px (m=2). LDS (halves):
// AK[0,36864) BV[36864,73728) B1[73728,77824) dentab(f32) @77824 (+1024h).
__global__ __launch_bounds__(512) void attn_ff1(
    const _Float16* __restrict__ xh, const _Float16* __restrict__ wf,
    const float* __restrict__ f1b, _Float16* __restrict__ t1g) {
  extern __shared__ _Float16 smem[];
  const int lane = threadIdx.x & 63, wid = threadIdx.x >> 6;
  const int l15 = lane & 15, q8 = (lane >> 4) * 8;
  const int row = blockIdx.x * 2 + (wid >> 2);
  const int rw = wid & 3;
  const int p0 = row * 128 + rw * 32;
  const int h = row & 127;
  const int w0 = rw * 32;
  float* dent = (float*)(smem + 77824) + wid * 64;   // [m2][h2][16] per wave

  // stage ALL weights (152 frags, 19/wave); in flight during qT + prologue
  {
    const _Float16* gw = wf + 4096 + (size_t)(wid * 19) * 512;
    _Float16* lw = smem + wid * 19 * 512;
    for (int i = 0; i < 19; ++i)
      gload_lds16(gw + i * 512 + lane * 8, lw + i * 512);
  }

  // own-x fragments + q^T tiles (global AQ reads overlap staging)
  half8 ax0[2], ax1[2];
#pragma unroll
  for (int m = 0; m < 2; ++m) {
    const _Float16* xp = xh + (size_t)(p0 + m * 16 + l15) * 64 + q8;
    ax0[m] = ldfrag(xp); ax1[m] = ldfrag(xp + 32);
  }
  f32x4 qT[2][4];
#pragma unroll
  for (int cb = 0; cb < 4; ++cb) {
    half8 aq0 = ldfrag(wf + (cb * 2 + 0) * 512 + lane * 8);
    half8 aq1 = ldfrag(wf + (cb * 2 + 1) * 512 + lane * 8);
#pragma unroll
    for (int m = 0; m < 2; ++m) {
      f32x4 c = {};
      c = mfma16(aq0, ax0[m], c);
      c = mfma16(aq1, ax1[m], c);
      qT[m][cb] = c;
    }
  }

  // shifted-x load helper (per tap)
  auto load_tap = [&](int t, half8 (&x0)[2], half8 (&x1)[2]) {
    const int dh = t / 3 - 1, dw = t % 3 - 1;
    const bool rk = (unsigned)(h + dh) < 128u;
#pragma unroll
    for (int m = 0; m < 2; ++m) {
      const bool cv = rk && ((unsigned)(w0 + m * 16 + l15 + dw) < 128u);
      const _Float16* sp = xh + (size_t)(p0 + m * 16 + l15 + dh * 128 + dw) * 64 + q8;
      x0[m] = cv ? ldfrag(sp) : zfrag();
      x1[m] = cv ? ldfrag(sp + 32) : zfrag();
    }
  };

  float den0[2] = {0.f, 0.f}, den1[2] = {0.f, 0.f};
  // score->exp for one tap; adds exp to den. OOB rows: sc=0 -> e=1 (mask sem.)
  auto score_tap = [&](int t, half8 (&x0)[2], half8 (&x1)[2],
                       float (&e0)[2], float (&e1)[2]) {
    const int dh = t / 3 - 1;
    const bool rowok = (unsigned)(h + dh) < 128u;   // block-uniform
#pragma unroll
    for (int m = 0; m < 2; ++m) {
      float pa = 0.f, pb = 0.f;
      if (rowok) {
#pragma unroll
        for (int cb = 0; cb < 4; ++cb) {
          f32x4 c = {};
          c = mfma16(ldfrag(smem + (t * 8 + cb * 2 + 0) * 512 + lane * 8), x0[m], c);
          c = mfma16(ldfrag(smem + (t * 8 + cb * 2 + 1) * 512 + lane * 8), x1[m], c);
          float d = qT[m][cb].x * c.x + qT[m][cb].y * c.y
                  + qT[m][cb].z * c.z + qT[m][cb].w * c.w;
          if (cb < 2) pa += d; else pb += d;
        }
        pa += __shfl_xor(pa, 16, 64); pa += __shfl_xor(pa, 32, 64);
        pb += __shfl_xor(pb, 16, 64); pb += __shfl_xor(pb, 32, 64);
      }
      e0[m] = __expf(pa * (1.f / 3.f));
      e1[m] = __expf(pb * (1.f / 3.f));
      den0[m] += e0[m]; den1[m] += e1[m];
    }
  };

  // prologue: tap-0 loads before the barrier (overlap staging drain)
  half8 sx0[2], sx1[2];
  load_tap(0, sx0, sx1);

  __syncthreads();                          // staging complete

  float e0c[2], e1c[2];
  score_tap(0, sx0, sx1, e0c, e1c);

  const _Float16* BVl = smem + 36864;
  f32x4 at[2][4];
#pragma unroll
  for (int m = 0; m < 2; ++m)
#pragma unroll
    for (int nb = 0; nb < 4; ++nb) at[m][nb] = f32x4{};

#pragma unroll
  for (int t = 0; t < 9; ++t) {
    const bool rowok = (unsigned)(h + (t / 3 - 1)) < 128u;
    half8 nx0[2], nx1[2];
    if (t < 8) load_tap(t + 1, nx0, nx1);   // loads for t+1 in flight
    if (rowok) {                            // V-accum for tap t (covers latency)
      half8 vf[8];
#pragma unroll
      for (int f = 0; f < 8; ++f) vf[f] = ldfrag(BVl + (t * 8 + f) * 512 + lane * 8);
#pragma unroll
      for (int m = 0; m < 2; ++m) {
        _Float16 h0 = (_Float16)e0c[m], h1 = (_Float16)e1c[m];
        half8 b0 = {h0, h0, h0, h0, h0, h0, h0, h0};
        half8 b1 = {h1, h1, h1, h1, h1, h1, h1, h1};
        half8 s00 = sx0[m] * b0, s01 = sx1[m] * b0;
        half8 s10 = sx0[m] * b1, s11 = sx1[m] * b1;
#pragma unroll
        for (int nb = 0; nb < 2; ++nb) {
          at[m][nb]     = mfma16(s00, vf[0 * 4 + nb],     at[m][nb]);
          at[m][nb]     = mfma16(s01, vf[1 * 4 + nb],     at[m][nb]);
          at[m][nb + 2] = mfma16(s10, vf[0 * 4 + nb + 2], at[m][nb + 2]);
          at[m][nb + 2] = mfma16(s11, vf[1 * 4 + nb + 2], at[m][nb + 2]);
        }
      }
    }
    if (t < 8) {
      float e0n[2], e1n[2];
      score_tap(t + 1, nx0, nx1, e0n, e1n); // scores for t+1
#pragma unroll
      for (int m = 0; m < 2; ++m) {
        sx0[m] = nx0[m]; sx1[m] = nx1[m];
        e0c[m] = e0n[m]; e1c[m] = e1n[m];
      }
    }
  }

  // per-pixel 1/den via per-wave LDS table (lane l15 = pixel)
#pragma unroll
  for (int m = 0; m < 2; ++m) {
    dent[(m * 2 + 0) * 16 + l15] = den0[m];
    dent[(m * 2 + 1) * 16 + l15] = den1[m];
  }
  f32x4 iv[2][2];
#pragma unroll
  for (int m = 0; m < 2; ++m)
#pragma unroll
    for (int hd = 0; hd < 2; ++hd) {
      f32x4 dv = *(const f32x4*)(dent + (m * 2 + hd) * 16 + (lane >> 4) * 4);
      iv[m][hd] = f32x4{1.f / dv.x, 1.f / dv.y, 1.f / dv.z, 1.f / dv.w};
    }

  // -------- ff1: normalize + transpose into AK region, then GEMM -----------
  __syncthreads();                          // all waves done reading AK/BV
  _Float16* myt = smem + wid * 2304;        // 8 x 2304 halves < AK region
#pragma unroll
  for (int m = 0; m < 2; ++m)
#pragma unroll
    for (int nb = 0; nb < 4; ++nb) {
      const int hd = nb >> 1;
#pragma unroll
      for (int r = 0; r < 4; ++r)
        myt[m * 1152 + ((lane >> 4) * 4 + r) * 72 + nb * 16 + l15] =
            (_Float16)(at[m][nb][r] * iv[m][hd][r]);
    }
  const _Float16* B1l = smem + 73728;
#pragma unroll
  for (int m = 0; m < 2; ++m) {
    half8 aa0 = ldfrag(myt + m * 1152 + l15 * 72 + q8);
    half8 aa1 = ldfrag(myt + m * 1152 + l15 * 72 + 32 + q8);
#pragma unroll
    for (int nb = 0; nb < 4; ++nb) {
      f32x4 c = {};
      c = mfma16(aa0, ldfrag(B1l + (0 * 4 + nb) * 512 + lane * 8), c);
      c = mfma16(aa1, ldfrag(B1l + (1 * 4 + nb) * 512 + lane * 8), c);
      float bv = f1b[nb * 16 + l15];
#pragma unroll
      for (int r = 0; r < 4; ++r) {
        float v = fmaxf(c[r] + bv, 0.f);
        t1g[(size_t)(p0 + m * 16 + (lane >> 4) * 4 + r) * 64 + nb * 16 + l15] = (_Float16)v;
      }
    }
  }
}

// ---------------- 3x3 conv, N-split: block = 2 rows x (COUT/2) channels ----
template <int KB, int NBL, int COUT>
__global__ __launch_bounds__(512, 2) void conv3x3(
    const _Float16* __restrict__ in, const _Float16* __restrict__ wfrag,
    const float* __restrict__ bias, void* __restrict__ outp, int out_fp32) {
  extern __shared__ _Float16 smem[];
  const int lane = threadIdx.x & 63, wid = threadIdx.x >> 6;
  const int l15 = lane & 15, q8 = (lane >> 4) * 8;
  const int nh = blockIdx.x & 1;
  const int pairIdx = blockIdx.x >> 1;
  const int row = pairIdx * 2 + (wid >> 2);
  const int rw = wid & 3;
  const int p0 = row * 128 + rw * 32;
  const int h = row & 127;
  const int w0 = rw * 32;
  const int CIN = KB * 32;
  const int NBF = COUT / 16;

  {
    for (int s = 0; s < 9; ++s) {
      int f = wid * 9 + s;
      int t = f >> 3, r = f & 7, kb = r / NBL, i = r % NBL;
      const _Float16* g = wfrag + (size_t)((t * KB + kb) * NBF + nh * NBL + i) * 512;
      gload_lds16(g + lane * 8, smem + f * 512);
    }
  }

  f32x4 acc[2][NBL];
#pragma unroll
  for (int m = 0; m < 2; ++m)
#pragma unroll
    for (int nb = 0; nb < NBL; ++nb) acc[m][nb] = f32x4{};

  half8 a[2][KB];
  {
    const bool rk = (unsigned)(h - 1) < 128u;
#pragma unroll
    for (int m = 0; m < 2; ++m) {
      const bool cv = rk && ((unsigned)(w0 + m * 16 + l15 - 1) < 128u);
      const _Float16* sp = in + (size_t)(p0 + m * 16 + l15 - 129) * CIN + q8;
#pragma unroll
      for (int kb = 0; kb < KB; ++kb) a[m][kb] = cv ? ldfrag(sp + kb * 32) : zfrag();
    }
  }

  __syncthreads();

#pragma unroll
  for (int t = 0; t < 9; ++t) {
    const int dh = t / 3 - 1;
    const bool rowok = (unsigned)(h + dh) < 128u;
    half8 an[2][KB];
    if (t < 8) {
      const int dh2 = (t + 1) / 3 - 1, dw2 = (t + 1) % 3 - 1;
      const bool rk2 = (unsigned)(h + dh2) < 128u;
#pragma unroll
      for (int m = 0; m < 2; ++m) {
        const bool cv = rk2 && ((unsigned)(w0 + m * 16 + l15 + dw2) < 128u);
        const _Float16* sp = in + (size_t)(p0 + m * 16 + l15 + dh2 * 128 + dw2) * CIN + q8;
#pragma unroll
        for (int kb = 0; kb < KB; ++kb) an[m][kb] = cv ? ldfrag(sp + kb * 32) : zfrag();
      }
    }
    if (rowok) {
#pragma unroll
      for (int nb = 0; nb < NBL; ++nb) {
#pragma unroll
        for (int kb = 0; kb < KB; ++kb) {
          half8 b = ldfrag(smem + (size_t)((t * KB + kb) * NBL + nb) * 512 + lane * 8);
          acc[0][nb] = mfma16(a[0][kb], b, acc[0][nb]);
          acc[1][nb] = mfma16(a[1][kb], b, acc[1][nb]);
        }
      }
    }
    if (t < 8) {
#pragma unroll
      for (int m = 0; m < 2; ++m)
#pragma unroll
        for (int kb = 0; kb < KB; ++kb) a[m][kb] = an[m][kb];
    }
  }

#pragma unroll
  for (int m = 0; m < 2; ++m)
#pragma unroll
    for (int nb = 0; nb < NBL; ++nb) {
      float bv = bias[nh * NBL * 16 + nb * 16 + l15];
#pragma unroll
      for (int r = 0; r < 4; ++r) {
        float v = fmaxf(acc[m][nb][r] + bv, 0.f);
        size_t idx = (size_t)(p0 + m * 16 + (lane >> 4) * 4 + r) * COUT
                   + nh * NBL * 16 + nb * 16 + l15;
        if (out_fp32) ((float*)outp)[idx] = v;
        else          ((_Float16*)outp)[idx] = (_Float16)v;
      }
    }
}

extern "C" void kernel_launch(void* const* d_in, const int* in_sizes, int n_in,
                              void* d_out, int out_size, void* d_ws, size_t ws_size,
                              hipStream_t stream) {
  (void)in_sizes; (void)n_in; (void)out_size; (void)ws_size;
  const float* x   = (const float*)d_in[0];
  const float* Kp  = (const float*)d_in[1];
  const float* Vp  = (const float*)d_in[2];
  const float* Qp  = (const float*)d_in[3];
  const float* f1w = (const float*)d_in[4];
  const float* f1b = (const float*)d_in[5];
  const float* f2w = (const float*)d_in[6];
  const float* f2b = (const float*)d_in[7];
  const float* f3w = (const float*)d_in[8];
  const float* f3b = (const float*)d_in[9];

  _Float16* xh  = (_Float16*)d_ws;
  _Float16* wf  = xh + 4194304;
  _Float16* t2g = wf + 229376;
  _Float16* t1g = (_Float16*)d_out;   // fp16 t1 in d_out, overwritten by conv3

  (void)hipFuncSetAttribute((const void*)attn_ff1,
      hipFuncAttributeMaxDynamicSharedMemorySize, 157696);
  (void)hipFuncSetAttribute((const void*)conv3x3<2, 4, 128>,
      hipFuncAttributeMaxDynamicSharedMemorySize, 73728);
  (void)hipFuncSetAttribute((const void*)conv3x3<4, 2, 64>,
      hipFuncAttributeMaxDynamicSharedMemorySize, 73728);

  prep<<<4992, 256, 0, stream>>>(x, Kp, Vp, Qp, f1w, f2w, f3w, xh, wf);
  attn_ff1<<<256, 512, 157696, stream>>>(xh, wf, f1b, t1g);
  conv3x3<2, 4, 128><<<512, 512, 73728, stream>>>(t1g, wf + 81920, f2b, t2g, 0);
  conv3x3<4, 2, 64><<<512, 512, 73728, stream>>>(t2g, wf + 155648, f3b, d_out, 1);
}